// Round 14
// baseline (266.599 us; speedup 1.0000x reference)
//
#include <hip/hip_runtime.h>
#include <hip/hip_bf16.h>
#include <hip/hip_cooperative_groups.h>

namespace cg = cooperative_groups;

#define Bn   128
#define Tn   256
#define Cn   256
#define T1n  128
#define T2n  64
#define TTn  448
#define EPSf 1e-5f

typedef __attribute__((ext_vector_type(8))) short short8;
typedef __attribute__((ext_vector_type(4))) short short4v;
typedef __attribute__((ext_vector_type(4))) float f32x4;

struct Params {
    const float *x, *cw1, *cb1, *cw2, *cb2, *ln1g, *ln1b, *ln2g, *ln2b, *tw1, *tb1, *tw2, *tb2;
    float* out;
    unsigned short *catb, *z1b, *w1rT, *w2rT, *wm1b, *wm2b;
    float *c1t, *c2t, *gt1, *bt1, *gt2, *bt2, *ps1, *ps2;
};

__device__ __forceinline__ unsigned short f2b(float f) {
    union { __hip_bfloat16 h; unsigned short u; } cv;
    cv.h = __float2bfloat16(f);   // RNE
    return cv.u;
}

__device__ __forceinline__ short8 cvt8(float4 a, float4 b) {
    short8 r;
    r[0] = (short)f2b(a.x); r[1] = (short)f2b(a.y); r[2] = (short)f2b(a.z); r[3] = (short)f2b(a.w);
    r[4] = (short)f2b(b.x); r[5] = (short)f2b(b.y); r[6] = (short)f2b(b.z); r[7] = (short)f2b(b.w);
    return r;
}

// ---------------- phase A1: prep (one 256-wide chunk per vb, 3488 total) ----------------
__device__ void prep_step(const Params& P, int vb) {
    int idx = vb * 256 + threadIdx.x;
    if (idx < 131072) {
        int co = idx >> 9, r = idx & 511, k = r >> 8, ci = r & 255;
        P.w1rT[idx] = f2b(P.cw1[(size_t)co * 512 + ci * 2 + k]);
    } else if ((idx -= 131072) < 262144) {
        int co = idx >> 10, r = idx & 1023, k = r >> 8, ci = r & 255;
        P.w2rT[idx] = f2b(P.cw2[(size_t)co * 1024 + ci * 4 + k]);
    } else if ((idx -= 262144) < 200704) {
        int i = idx / TTn, j = idx % TTn;
        P.wm1b[idx] = (j <= i) ? f2b(P.tw1[(size_t)j * TTn + i]) : (unsigned short)0;
    } else if ((idx -= 200704) < 200704) {
        int i = idx / TTn, j = idx % TTn;
        P.wm2b[idx] = (j <= i) ? f2b(P.tw2[(size_t)j * TTn + i]) : (unsigned short)0;
    } else if ((idx -= 200704) < 32768) {
        int c = idx >> 7, r = idx & 127;
        P.gt1[idx] = P.ln1g[(size_t)r * Cn + c];
    } else if ((idx -= 32768) < 32768) {
        int c = idx >> 7, r = idx & 127;
        P.bt1[idx] = P.ln1b[(size_t)r * Cn + c];
    } else if ((idx -= 32768) < 16384) {
        int c = idx >> 6, r = idx & 63;
        P.gt2[idx] = P.ln2g[(size_t)r * Cn + c];
    } else if ((idx -= 16384) < 16384) {
        int c = idx >> 6, r = idx & 63;
        P.bt2[idx] = P.ln2b[(size_t)r * Cn + c];
    }
}

// ---------------- phase A2: x transpose tile (2048 vb: b=vb>>4, t0=((vb>>2)&3)*64, c0=(vb&3)*64) ----------------
__device__ void xpose_tile(char* smem, const Params& P, int vb) {
    float (*tl)[65] = (float(*)[65])smem;
    int b = vb >> 4, r = vb & 15;
    int t0 = (r >> 2) * 64, c0 = (r & 3) * 64;
    const float* xp = P.x + (size_t)b * Tn * Cn;
    int lr = threadIdx.x >> 4;
    int lc = (threadIdx.x & 15) * 4;
#pragma unroll
    for (int rr = 0; rr < 4; ++rr) {
        int row = lr + rr * 16;
        float4 v = *(const float4*)(xp + (size_t)(t0 + row) * Cn + c0 + lc);
        tl[lc + 0][row] = v.x; tl[lc + 1][row] = v.y;
        tl[lc + 2][row] = v.z; tl[lc + 3][row] = v.w;
    }
    __syncthreads();
    int cr = threadIdx.x >> 2, tq = (threadIdx.x & 3) * 16;
    unsigned short* qp = P.catb + (size_t)b * (TTn * Cn) + (size_t)(c0 + cr) * TTn + t0 + tq;
    short8 o0, o1;
#pragma unroll
    for (int j = 0; j < 8; ++j) {
        o0[j] = (short)f2b(tl[cr][tq + j]);
        o1[j] = (short)f2b(tl[cr][tq + 8 + j]);
    }
    *(short8*)(qp) = o0;
    *(short8*)(qp + 8) = o1;
}

// ---------------- phase B: conv GEMM unit (dbuf, 1 barrier/k-tile) ----------------
__device__ void conv_body(char* smem,
        const float* __restrict__ x, int lda,
        const unsigned short* __restrict__ Bw,
        const float* __restrict__ bias,
        float* __restrict__ Cout, long cstride, int ldc, int K,
        float* __restrict__ psout, int slot, int nslots,
        int m0, int n0, int bz) {
    const int tid = threadIdx.x;
    const int lane = tid & 63;
    const int wid = tid >> 6;
    const int wr = wid >> 1, wc = wid & 1;

    const int ar = tid >> 2, akq = tid & 3;
    const int bn_ = tid >> 1, bkh = (tid & 1) * 32;

    const float* Afp = x + (size_t)bz * (Tn * Cn) + (size_t)(m0 + ar) * lda + akq * 16;
    const unsigned short* Bp = Bw + (size_t)(n0 + bn_) * K + bkh;

    const int awb = ar * 128 + akq * 32;
    const int aswz = (ar & 7) << 4;
    const int bwb = bn_ * 128 + bkh * 2;
    const int bswz = (bn_ & 7) << 4;

    short8 ra0, ra1, rb0, rb1, rb2, rb3;
    auto loadA = [&](int k0) {
        const float* p = Afp + k0;
        float4 v0 = *(const float4*)(p);
        float4 v1 = *(const float4*)(p + 4);
        float4 v2 = *(const float4*)(p + 8);
        float4 v3 = *(const float4*)(p + 12);
        ra0 = cvt8(v0, v1);
        ra1 = cvt8(v2, v3);
    };
    auto loadB = [&](int k0) {
        rb0 = *(const short8*)(Bp + k0);
        rb1 = *(const short8*)(Bp + k0 + 8);
        rb2 = *(const short8*)(Bp + k0 + 16);
        rb3 = *(const short8*)(Bp + k0 + 24);
    };
    auto stage = [&](int buf) {
        char* AsB = smem + buf * 8192;
        char* BsB = smem + 16384 + buf * 16384;
        *(short8*)(AsB + ((awb) ^ aswz)) = ra0;
        *(short8*)(AsB + ((awb + 16) ^ aswz)) = ra1;
        *(short8*)(BsB + ((bwb) ^ bswz)) = rb0;
        *(short8*)(BsB + ((bwb + 16) ^ bswz)) = rb1;
        *(short8*)(BsB + ((bwb + 32) ^ bswz)) = rb2;
        *(short8*)(BsB + ((bwb + 48) ^ bswz)) = rb3;
    };

    const int fl = lane & 15;
    const int fkb = (lane >> 4) * 16;
    const int amb = (wr * 32 + fl) * 128;
    const int bnb = (wc * 64 + fl) * 128;
    const int fswz = (fl & 7) << 4;

    f32x4 acc[2][4];
#pragma unroll
    for (int i = 0; i < 2; ++i)
#pragma unroll
        for (int j = 0; j < 4; ++j) acc[i][j] = (f32x4){0.f, 0.f, 0.f, 0.f};

    const int nkt = K >> 6;
    loadA(0); loadB(0);
    stage(0);
    __syncthreads();
    for (int kt = 0; kt < nkt; ++kt) {
        const int cur = kt & 1;
        if (kt + 1 < nkt) { loadA((kt + 1) * 64); loadB((kt + 1) * 64); }
        char* AsB = smem + cur * 8192;
        char* BsB = smem + 16384 + cur * 16384;
#pragma unroll
        for (int ks = 0; ks < 2; ++ks) {
            const int kb = ks * 64 + fkb;
            short8 af0 = *(const short8*)(AsB + ((amb + kb) ^ fswz));
            short8 af1 = *(const short8*)(AsB + ((amb + 2048 + kb) ^ fswz));
            short8 bf0 = *(const short8*)(BsB + ((bnb + kb) ^ fswz));
            short8 bf1 = *(const short8*)(BsB + ((bnb + 2048 + kb) ^ fswz));
            short8 bf2 = *(const short8*)(BsB + ((bnb + 4096 + kb) ^ fswz));
            short8 bf3 = *(const short8*)(BsB + ((bnb + 6144 + kb) ^ fswz));
            acc[0][0] = __builtin_amdgcn_mfma_f32_16x16x32_bf16(af0, bf0, acc[0][0], 0, 0, 0);
            acc[0][1] = __builtin_amdgcn_mfma_f32_16x16x32_bf16(af0, bf1, acc[0][1], 0, 0, 0);
            acc[0][2] = __builtin_amdgcn_mfma_f32_16x16x32_bf16(af0, bf2, acc[0][2], 0, 0, 0);
            acc[0][3] = __builtin_amdgcn_mfma_f32_16x16x32_bf16(af0, bf3, acc[0][3], 0, 0, 0);
            acc[1][0] = __builtin_amdgcn_mfma_f32_16x16x32_bf16(af1, bf0, acc[1][0], 0, 0, 0);
            acc[1][1] = __builtin_amdgcn_mfma_f32_16x16x32_bf16(af1, bf1, acc[1][1], 0, 0, 0);
            acc[1][2] = __builtin_amdgcn_mfma_f32_16x16x32_bf16(af1, bf2, acc[1][2], 0, 0, 0);
            acc[1][3] = __builtin_amdgcn_mfma_f32_16x16x32_bf16(af1, bf3, acc[1][3], 0, 0, 0);
        }
        if (kt + 1 < nkt) stage(cur ^ 1);
        __syncthreads();
    }

    const int lrow = (lane >> 4) * 4;
    float s_ = 0.f, ss_ = 0.f;
#pragma unroll
    for (int mf = 0; mf < 2; ++mf) {
        const int trow = m0 + wr * 32 + mf * 16 + lrow;
#pragma unroll
        for (int nf = 0; nf < 4; ++nf) {
            const int col = n0 + wc * 64 + nf * 16 + fl;
            f32x4 v = acc[mf][nf];
            v += bias[col];
#pragma unroll
            for (int r = 0; r < 4; ++r) { s_ += v[r]; ss_ = fmaf(v[r], v[r], ss_); }
            float* Cb = Cout + (size_t)bz * cstride + (size_t)col * ldc + trow;
            *(f32x4*)Cb = v;
        }
    }

#pragma unroll
    for (int o = 32; o > 0; o >>= 1) { s_ += __shfl_down(s_, o); ss_ += __shfl_down(ss_, o); }
    float* rsm = (float*)smem;
    if (lane == 0) { rsm[wid] = s_; rsm[wid + 4] = ss_; }
    __syncthreads();
    if (tid == 0) {
        float S = rsm[0] + rsm[1] + rsm[2] + rsm[3];
        float SS = rsm[4] + rsm[5] + rsm[6] + rsm[7];
        psout[((size_t)bz * nslots + slot) * 2 + 0] = S;
        psout[((size_t)bz * nslots + slot) * 2 + 1] = SS;
    }
    __syncthreads();   // protect rsm/LDS before next virtual iteration restages
}

__device__ void conv_unit(char* smem, const Params& P, int vb) {
    const int bz = vb & 127;
    const int u = vb >> 7;           // 0..5
    if (u < 4) {
        conv_body(smem, P.x, 512, P.w1rT, P.cb1, P.c1t, (long)Cn * T1n, T1n, 512,
                  P.ps1, u, 4, (u >> 1) * 64, (u & 1) * 128, bz);
    } else {
        conv_body(smem, P.x, 1024, P.w2rT, P.cb2, P.c2t, (long)Cn * T2n, T2n, 1024,
                  P.ps2, u - 4, 2, 0, (u - 4) * 128, bz);
    }
}

// ---------------- phase C: layernorm apply (3072 vb: bx=vb%24, b=vb/24) ----------------
__device__ void ln_unit(const Params& P, int vb) {
    const int bx = vb % 24, b = vb / 24;
    const float *p, *g, *be;
    unsigned short* q;
    int LG, n, base;
    float S = 0.f, SS = 0.f;
    if (bx < 16) {
        n = Cn * T1n; LG = 7;
        p = P.c1t + (size_t)b * n; g = P.gt1; be = P.bt1;
        q = P.catb + (size_t)b * (TTn * Cn) + Tn;
#pragma unroll
        for (int s_ = 0; s_ < 4; ++s_) { S += P.ps1[b * 8 + s_ * 2]; SS += P.ps1[b * 8 + s_ * 2 + 1]; }
        base = bx * 2048;
    } else {
        n = Cn * T2n; LG = 6;
        p = P.c2t + (size_t)b * n; g = P.gt2; be = P.bt2;
        q = P.catb + (size_t)b * (TTn * Cn) + Tn + T1n;
#pragma unroll
        for (int s_ = 0; s_ < 2; ++s_) { S += P.ps2[b * 4 + s_ * 2]; SS += P.ps2[b * 4 + s_ * 2 + 1]; }
        base = (bx - 16) * 2048;
    }
    float mu = S / n;
    float rs = rsqrtf(SS / n - mu * mu + EPSf);

    int i = base + threadIdx.x * 8;
    int c = i >> LG, t = i & ((1 << LG) - 1);
    float4 v0 = *(const float4*)(p + i);
    float4 v1 = *(const float4*)(p + i + 4);
    float4 g0 = *(const float4*)(g + i);
    float4 g1 = *(const float4*)(g + i + 4);
    float4 b0 = *(const float4*)(be + i);
    float4 b1 = *(const float4*)(be + i + 4);
    float4 o0, o1;
    o0.x = fmaf((v0.x - mu) * rs, g0.x, b0.x);
    o0.y = fmaf((v0.y - mu) * rs, g0.y, b0.y);
    o0.z = fmaf((v0.z - mu) * rs, g0.z, b0.z);
    o0.w = fmaf((v0.w - mu) * rs, g0.w, b0.w);
    o1.x = fmaf((v1.x - mu) * rs, g1.x, b1.x);
    o1.y = fmaf((v1.y - mu) * rs, g1.y, b1.y);
    o1.z = fmaf((v1.z - mu) * rs, g1.z, b1.z);
    o1.w = fmaf((v1.w - mu) * rs, g1.w, b1.w);
    *(short8*)(q + (size_t)c * TTn + t) = cvt8(o0, o1);
}

// ---------------- phase D/E: TriU GEMM unit (flat-N, dbuf, XCD-swizzled on vb) ----------------
template<int EPI>
__device__ void triu_unit(char* smem,
                          const unsigned short* __restrict__ Asrc,
                          const unsigned short* __restrict__ Bsrc,
                          const float* __restrict__ bias,
                          void* __restrict__ Cv, int vb) {
    const int tid = threadIdx.x;
    const int lane = tid & 63;
    const int wid = tid >> 6;
    const int wr = wid >> 1, wc = wid & 1;

    const int xcd = vb & 7, seq = vb >> 3;
    const int m0 = (seq % 7) * 64;
    const long n0 = (long)(xcd * 32 + seq / 7) * 128;   // flat (b,c) row index

    // As[2] @ 0 (2*8192), Bs[2] @ 16384 (2*16384)
    const int ar = tid >> 2, akq = tid & 3;
    const int bn_ = tid >> 1, bkh = (tid & 1) * 32;

    const unsigned short* Ap = Asrc + (size_t)(m0 + ar) * TTn + akq * 16;
    const unsigned short* Bp = Bsrc + (size_t)(n0 + bn_) * TTn + bkh;

    const int awb = ar * 128 + akq * 32;
    const int aswz = (ar & 7) << 4;
    const int bwb = bn_ * 128 + bkh * 2;
    const int bswz = (bn_ & 7) << 4;

    short8 ra0, ra1, rb[4];
    auto loadAB = [&](int k0) {
        ra0 = *(const short8*)(Ap + k0);
        ra1 = *(const short8*)(Ap + k0 + 8);
#pragma unroll
        for (int j = 0; j < 4; ++j) rb[j] = *(const short8*)(Bp + k0 + j * 8);
    };
    auto stage = [&](int buf) {
        char* AsB = smem + buf * 8192;
        char* BsB = smem + 16384 + buf * 16384;
        *(short8*)(AsB + ((awb) ^ aswz)) = ra0;
        *(short8*)(AsB + ((awb + 16) ^ aswz)) = ra1;
#pragma unroll
        for (int j = 0; j < 4; ++j)
            *(short8*)(BsB + ((bwb + j * 16) ^ bswz)) = rb[j];
    };

    const int fl = lane & 15;
    const int fkb = (lane >> 4) * 16;
    const int amb = (wr * 32 + fl) * 128;
    const int bnb = (wc * 64 + fl) * 128;
    const int fswz = (fl & 7) << 4;

    f32x4 acc[2][4];
#pragma unroll
    for (int i = 0; i < 2; ++i)
#pragma unroll
        for (int j = 0; j < 4; ++j) acc[i][j] = (f32x4){0.f, 0.f, 0.f, 0.f};

    const int nkt = (m0 >> 6) + 1;   // triangular skip

    loadAB(0);
    stage(0);
    __syncthreads();
    for (int kt = 0; kt < nkt; ++kt) {
        const int cur = kt & 1;
        if (kt + 1 < nkt) loadAB((kt + 1) * 64);
        char* AsB = smem + cur * 8192;
        char* BsB = smem + 16384 + cur * 16384;
#pragma unroll
        for (int ks = 0; ks < 2; ++ks) {
            const int kb = ks * 64 + fkb;
            short8 af0 = *(const short8*)(AsB + ((amb + kb) ^ fswz));
            short8 af1 = *(const short8*)(AsB + ((amb + 2048 + kb) ^ fswz));
            short8 bf0 = *(const short8*)(BsB + ((bnb + kb) ^ fswz));
            short8 bf1 = *(const short8*)(BsB + ((bnb + 2048 + kb) ^ fswz));
            short8 bf2 = *(const short8*)(BsB + ((bnb + 4096 + kb) ^ fswz));
            short8 bf3 = *(const short8*)(BsB + ((bnb + 6144 + kb) ^ fswz));
            acc[0][0] = __builtin_amdgcn_mfma_f32_16x16x32_bf16(af0, bf0, acc[0][0], 0, 0, 0);
            acc[0][1] = __builtin_amdgcn_mfma_f32_16x16x32_bf16(af0, bf1, acc[0][1], 0, 0, 0);
            acc[0][2] = __builtin_amdgcn_mfma_f32_16x16x32_bf16(af0, bf2, acc[0][2], 0, 0, 0);
            acc[0][3] = __builtin_amdgcn_mfma_f32_16x16x32_bf16(af0, bf3, acc[0][3], 0, 0, 0);
            acc[1][0] = __builtin_amdgcn_mfma_f32_16x16x32_bf16(af1, bf0, acc[1][0], 0, 0, 0);
            acc[1][1] = __builtin_amdgcn_mfma_f32_16x16x32_bf16(af1, bf1, acc[1][1], 0, 0, 0);
            acc[1][2] = __builtin_amdgcn_mfma_f32_16x16x32_bf16(af1, bf2, acc[1][2], 0, 0, 0);
            acc[1][3] = __builtin_amdgcn_mfma_f32_16x16x32_bf16(af1, bf3, acc[1][3], 0, 0, 0);
        }
        if (kt + 1 < nkt) stage(cur ^ 1);
        __syncthreads();
    }

    const int lrow = (lane >> 4) * 4;
#pragma unroll
    for (int mf = 0; mf < 2; ++mf) {
        const int trow = m0 + wr * 32 + mf * 16 + lrow;
        f32x4 bv = *(const f32x4*)(bias + trow);
#pragma unroll
        for (int nf = 0; nf < 4; ++nf) {
            const long coln = n0 + wc * 64 + nf * 16 + fl;
            f32x4 v = acc[mf][nf] + bv;
            if (EPI == 1) {
                unsigned short* Cb = (unsigned short*)Cv + (size_t)coln * TTn + trow;
                short4v pk;
#pragma unroll
                for (int r = 0; r < 4; ++r) {
                    float t = v[r];
                    float u = fminf(fmaxf(t + 3.f, 0.f), 6.f);
                    t = t * u * (1.f / 6.f);
                    pk[r] = (short)f2b(t);
                }
                *(short4v*)Cb = pk;
            } else {
                const int b = (int)(coln >> 8), c = (int)(coln & 255);
                float* Cb = (float*)Cv + ((size_t)b * TTn + trow) * Cn + c;
#pragma unroll
                for (int r = 0; r < 4; ++r) Cb[(size_t)r * Cn] = v[r];
            }
        }
    }
    // no trailing barrier needed: all LDS reads finished at the loop's final barrier,
    // and the next virtual iteration stages before its own barrier.
}

// ---------------- the one cooperative kernel ----------------
__global__ __launch_bounds__(256, 3) void fused_all(Params P) {
    __shared__ alignas(16) char smem[49152];
    cg::grid_group grid = cg::this_grid();
    const int G = gridDim.x, bid = blockIdx.x;

    // phase A: prep + x-transpose (independent of each other)
    for (int vb = bid; vb < 3488; vb += G) prep_step(P, vb);
    for (int vb = bid; vb < 2048; vb += G) { xpose_tile(smem, P, vb); __syncthreads(); }
    grid.sync();

    // phase B: conv1 + conv2 (+ LN partial sums)
    for (int vb = bid; vb < 768; vb += G) conv_unit(smem, P, vb);
    grid.sync();

    // phase C: layernorm apply -> catb rows [256,448)
    for (int vb = bid; vb < 3072; vb += G) ln_unit(P, vb);
    grid.sync();

    // phase D: TriU layer 1 -> z1b (bf16, hardswish)
    for (int vb = bid; vb < 1792; vb += G) triu_unit<1>(smem, P.wm1b, P.catb, P.tb1, P.z1b, vb);
    grid.sync();

    // phase E: TriU layer 2 -> out (f32 [b][t][c])
    for (int vb = bid; vb < 1792; vb += G) triu_unit<2>(smem, P.wm2b, P.z1b, P.tb2, P.out, vb);
}

// ---------------- launch ----------------
extern "C" void kernel_launch(void* const* d_in, const int* in_sizes, int n_in,
                              void* d_out, int out_size, void* d_ws, size_t ws_size,
                              hipStream_t stream) {
    char* w = (char*)d_ws;
    Params P;
    P.x    = (const float*)d_in[0];
    P.cw1  = (const float*)d_in[1];
    P.cb1  = (const float*)d_in[2];
    P.cw2  = (const float*)d_in[3];
    P.cb2  = (const float*)d_in[4];
    P.ln1g = (const float*)d_in[5];
    P.ln1b = (const float*)d_in[6];
    P.ln2g = (const float*)d_in[7];
    P.ln2b = (const float*)d_in[8];
    P.tw1  = (const float*)d_in[9];
    P.tb1  = (const float*)d_in[10];
    P.tw2  = (const float*)d_in[11];
    P.tb2  = (const float*)d_in[12];
    P.out  = (float*)d_out;
    P.catb = (unsigned short*)w;                   // bf16 [B][C][448]  29,360,128 B
    P.z1b  = (unsigned short*)(w + 29360128);      // bf16 [B][C][448]  29,360,128 B
    P.c1t  = (float*)(w + 58720256);               // f32 [B][C][128]   16,777,216 B
    P.c2t  = (float*)(w + 75497472);               // f32 [B][C][64]     8,388,608 B
    P.w1rT = (unsigned short*)(w + 83886080);
    P.w2rT = (unsigned short*)(w + 84148224);
    P.wm1b = (unsigned short*)(w + 84672512);
    P.wm2b = (unsigned short*)(w + 85073920);
    P.gt1  = (float*)(w + 85475328);
    P.bt1  = (float*)(w + 85606400);
    P.gt2  = (float*)(w + 85737472);
    P.bt2  = (float*)(w + 85803008);
    P.ps1  = (float*)(w + 85868544);               // [B][4][2] = 4096 B
    P.ps2  = (float*)(w + 85872640);               // [B][2][2] = 2048 B

    // cooperative grid size: min(768, occupancy * CUs), multiple of 8 (XCD swizzle invariant)
    int perCU = 0;
    hipOccupancyMaxActiveBlocksPerMultiprocessor(&perCU, fused_all, 256, 0);
    if (perCU < 1) perCU = 1;
    int nCU = 256;
    hipDeviceProp_t prop;
    int dev = 0;
    if (hipGetDevice(&dev) == hipSuccess && hipGetDeviceProperties(&prop, dev) == hipSuccess)
        nCU = prop.multiProcessorCount;
    long grid = (long)perCU * nCU;
    if (grid > 768) grid = 768;
    grid &= ~7L;
    if (grid < 8) grid = 8;

    void* kargs[] = { (void*)&P };
    hipLaunchCooperativeKernel((const void*)fused_all, dim3((unsigned)grid), dim3(256), kargs, 0, stream);
}

// Round 15
// 93.303 us; speedup vs baseline: 2.8573x; 2.8573x over previous
//
#include <hip/hip_runtime.h>
#include <hip/hip_bf16.h>

#define Bn   128
#define Tn   256
#define Cn   256
#define T1n  128
#define T2n  64
#define TTn  448
#define EPSf 1e-5f

typedef __attribute__((ext_vector_type(8))) short short8;
typedef __attribute__((ext_vector_type(4))) short short4v;
typedef __attribute__((ext_vector_type(4))) float f32x4;

__device__ __forceinline__ unsigned short f2b(float f) {
    union { __hip_bfloat16 h; unsigned short u; } cv;
    cv.h = __float2bfloat16(f);   // RNE
    return cv.u;
}

__device__ __forceinline__ float b2f(unsigned short u) {
    union { float f; unsigned v; } c;
    c.v = (unsigned)u << 16;
    return c.f;
}

__device__ __forceinline__ short8 cvt8(float4 a, float4 b) {
    short8 r;
    r[0] = (short)f2b(a.x); r[1] = (short)f2b(a.y); r[2] = (short)f2b(a.z); r[3] = (short)f2b(a.w);
    r[4] = (short)f2b(b.x); r[5] = (short)f2b(b.y); r[6] = (short)f2b(b.z); r[7] = (short)f2b(b.w);
    return r;
}

// ---------------- merged prep + x-transpose ----------------
// vb < 2048: xpose tile (b=vb>>4, t0=((vb>>2)&3)*64, c0=(vb&3)*64)
// vb >= 2048: prep flat chunk (idx = (vb-2048)*256 + tid, 892928 elems -> 3488 chunks)
__global__ __launch_bounds__(256) void prep_xpose(
        const float* __restrict__ x,
        const float* __restrict__ cw1, const float* __restrict__ cw2,
        const float* __restrict__ tw1, const float* __restrict__ tw2,
        const float* __restrict__ ln1g, const float* __restrict__ ln1b,
        const float* __restrict__ ln2g, const float* __restrict__ ln2b,
        unsigned short* __restrict__ catb,
        unsigned short* __restrict__ w1rT, unsigned short* __restrict__ w2rT,
        unsigned short* __restrict__ wm1b, unsigned short* __restrict__ wm2b,
        float* __restrict__ gt1, float* __restrict__ bt1,
        float* __restrict__ gt2, float* __restrict__ bt2) {
    __shared__ float tl[64][65];
    const int vb = blockIdx.x;
    if (vb < 2048) {
        int b = vb >> 4, r = vb & 15;
        int t0 = ((r >> 2) & 3) * 64, c0 = (r & 3) * 64;
        const float* xp = x + (size_t)b * Tn * Cn;
        int lr = threadIdx.x >> 4;
        int lc = (threadIdx.x & 15) * 4;
#pragma unroll
        for (int rr = 0; rr < 4; ++rr) {
            int row = lr + rr * 16;
            float4 v = *(const float4*)(xp + (size_t)(t0 + row) * Cn + c0 + lc);
            tl[lc + 0][row] = v.x; tl[lc + 1][row] = v.y;
            tl[lc + 2][row] = v.z; tl[lc + 3][row] = v.w;
        }
        __syncthreads();
        int cr = threadIdx.x >> 2, tq = (threadIdx.x & 3) * 16;
        unsigned short* qp = catb + (size_t)b * (TTn * Cn) + (size_t)(c0 + cr) * TTn + t0 + tq;
        short8 o0, o1;
#pragma unroll
        for (int j = 0; j < 8; ++j) {
            o0[j] = (short)f2b(tl[cr][tq + j]);
            o1[j] = (short)f2b(tl[cr][tq + 8 + j]);
        }
        *(short8*)(qp) = o0;
        *(short8*)(qp + 8) = o1;
        return;
    }
    int idx = (vb - 2048) * 256 + threadIdx.x;
    if (idx < 131072) {
        int co = idx >> 9, r = idx & 511, k = r >> 8, ci = r & 255;
        w1rT[idx] = f2b(cw1[(size_t)co * 512 + ci * 2 + k]);
    } else if ((idx -= 131072) < 262144) {
        int co = idx >> 10, r = idx & 1023, k = r >> 8, ci = r & 255;
        w2rT[idx] = f2b(cw2[(size_t)co * 1024 + ci * 4 + k]);
    } else if ((idx -= 262144) < 200704) {
        int i = idx / TTn, j = idx % TTn;
        wm1b[idx] = (j <= i) ? f2b(tw1[(size_t)j * TTn + i]) : (unsigned short)0;
    } else if ((idx -= 200704) < 200704) {
        int i = idx / TTn, j = idx % TTn;
        wm2b[idx] = (j <= i) ? f2b(tw2[(size_t)j * TTn + i]) : (unsigned short)0;
    } else if ((idx -= 200704) < 32768) {
        int c = idx >> 7, r = idx & 127;
        gt1[idx] = ln1g[(size_t)r * Cn + c];
    } else if ((idx -= 32768) < 32768) {
        int c = idx >> 7, r = idx & 127;
        bt1[idx] = ln1b[(size_t)r * Cn + c];
    } else if ((idx -= 32768) < 16384) {
        int c = idx >> 6, r = idx & 63;
        gt2[idx] = ln2g[(size_t)r * Cn + c];
    } else if ((idx -= 16384) < 16384) {
        int c = idx >> 6, r = idx & 63;
        bt2[idx] = ln2b[(size_t)r * Cn + c];
    }
}

// ---------------- conv GEMM body (BM=64 BN=128 BK=64), dbuf, bf16 slab output ----------------
__device__ __forceinline__ void conv_body(char* smem,
        const float* __restrict__ x, int lda,
        const unsigned short* __restrict__ Bw,
        const float* __restrict__ bias,
        unsigned short* __restrict__ Cout, long cstride, int ldc, int K,
        float* __restrict__ psout, int slot, int nslots,
        int m0, int n0, int bz) {
    const int tid = threadIdx.x;
    const int lane = tid & 63;
    const int wid = tid >> 6;
    const int wr = wid >> 1, wc = wid & 1;

    const int ar = tid >> 2, akq = tid & 3;
    const int bn_ = tid >> 1, bkh = (tid & 1) * 32;

    const float* Afp = x + (size_t)bz * (Tn * Cn) + (size_t)(m0 + ar) * lda + akq * 16;
    const unsigned short* Bp = Bw + (size_t)(n0 + bn_) * K + bkh;

    const int awb = ar * 128 + akq * 32;
    const int aswz = (ar & 7) << 4;
    const int bwb = bn_ * 128 + bkh * 2;
    const int bswz = (bn_ & 7) << 4;

    short8 ra0, ra1, rb0, rb1, rb2, rb3;
    auto loadA = [&](int k0) {
        const float* p = Afp + k0;
        float4 v0 = *(const float4*)(p);
        float4 v1 = *(const float4*)(p + 4);
        float4 v2 = *(const float4*)(p + 8);
        float4 v3 = *(const float4*)(p + 12);
        ra0 = cvt8(v0, v1);
        ra1 = cvt8(v2, v3);
    };
    auto loadB = [&](int k0) {
        rb0 = *(const short8*)(Bp + k0);
        rb1 = *(const short8*)(Bp + k0 + 8);
        rb2 = *(const short8*)(Bp + k0 + 16);
        rb3 = *(const short8*)(Bp + k0 + 24);
    };
    auto stage = [&](int buf) {
        char* AsB = smem + buf * 8192;
        char* BsB = smem + 16384 + buf * 16384;
        *(short8*)(AsB + ((awb) ^ aswz)) = ra0;
        *(short8*)(AsB + ((awb + 16) ^ aswz)) = ra1;
        *(short8*)(BsB + ((bwb) ^ bswz)) = rb0;
        *(short8*)(BsB + ((bwb + 16) ^ bswz)) = rb1;
        *(short8*)(BsB + ((bwb + 32) ^ bswz)) = rb2;
        *(short8*)(BsB + ((bwb + 48) ^ bswz)) = rb3;
    };

    const int fl = lane & 15;
    const int fkb = (lane >> 4) * 16;
    const int amb = (wr * 32 + fl) * 128;
    const int bnb = (wc * 64 + fl) * 128;
    const int fswz = (fl & 7) << 4;

    f32x4 acc[2][4];
#pragma unroll
    for (int i = 0; i < 2; ++i)
#pragma unroll
        for (int j = 0; j < 4; ++j) acc[i][j] = (f32x4){0.f, 0.f, 0.f, 0.f};

    const int nkt = K >> 6;
    loadA(0); loadB(0);
    stage(0);
    __syncthreads();
    for (int kt = 0; kt < nkt; ++kt) {
        const int cur = kt & 1;
        if (kt + 1 < nkt) { loadA((kt + 1) * 64); loadB((kt + 1) * 64); }
        char* AsB = smem + cur * 8192;
        char* BsB = smem + 16384 + cur * 16384;
#pragma unroll
        for (int ks = 0; ks < 2; ++ks) {
            const int kb = ks * 64 + fkb;
            short8 af0 = *(const short8*)(AsB + ((amb + kb) ^ fswz));
            short8 af1 = *(const short8*)(AsB + ((amb + 2048 + kb) ^ fswz));
            short8 bf0 = *(const short8*)(BsB + ((bnb + kb) ^ fswz));
            short8 bf1 = *(const short8*)(BsB + ((bnb + 2048 + kb) ^ fswz));
            short8 bf2 = *(const short8*)(BsB + ((bnb + 4096 + kb) ^ fswz));
            short8 bf3 = *(const short8*)(BsB + ((bnb + 6144 + kb) ^ fswz));
            acc[0][0] = __builtin_amdgcn_mfma_f32_16x16x32_bf16(af0, bf0, acc[0][0], 0, 0, 0);
            acc[0][1] = __builtin_amdgcn_mfma_f32_16x16x32_bf16(af0, bf1, acc[0][1], 0, 0, 0);
            acc[0][2] = __builtin_amdgcn_mfma_f32_16x16x32_bf16(af0, bf2, acc[0][2], 0, 0, 0);
            acc[0][3] = __builtin_amdgcn_mfma_f32_16x16x32_bf16(af0, bf3, acc[0][3], 0, 0, 0);
            acc[1][0] = __builtin_amdgcn_mfma_f32_16x16x32_bf16(af1, bf0, acc[1][0], 0, 0, 0);
            acc[1][1] = __builtin_amdgcn_mfma_f32_16x16x32_bf16(af1, bf1, acc[1][1], 0, 0, 0);
            acc[1][2] = __builtin_amdgcn_mfma_f32_16x16x32_bf16(af1, bf2, acc[1][2], 0, 0, 0);
            acc[1][3] = __builtin_amdgcn_mfma_f32_16x16x32_bf16(af1, bf3, acc[1][3], 0, 0, 0);
        }
        if (kt + 1 < nkt) stage(cur ^ 1);
        __syncthreads();
    }

    const int lrow = (lane >> 4) * 4;
    float s_ = 0.f, ss_ = 0.f;
#pragma unroll
    for (int mf = 0; mf < 2; ++mf) {
        const int trow = m0 + wr * 32 + mf * 16 + lrow;
#pragma unroll
        for (int nf = 0; nf < 4; ++nf) {
            const int col = n0 + wc * 64 + nf * 16 + fl;
            f32x4 v = acc[mf][nf];
            v += bias[col];
            short4v pk;
#pragma unroll
            for (int r = 0; r < 4; ++r) {
                s_ += v[r]; ss_ = fmaf(v[r], v[r], ss_);
                pk[r] = (short)f2b(v[r]);
            }
            unsigned short* Cb = Cout + (size_t)bz * cstride + (size_t)col * ldc + trow;
            *(short4v*)Cb = pk;
        }
    }

#pragma unroll
    for (int o = 32; o > 0; o >>= 1) { s_ += __shfl_down(s_, o); ss_ += __shfl_down(ss_, o); }
    float* rsm = (float*)smem;
    if (lane == 0) { rsm[wid] = s_; rsm[wid + 4] = ss_; }
    __syncthreads();
    if (tid == 0) {
        float S = rsm[0] + rsm[1] + rsm[2] + rsm[3];
        float SS = rsm[4] + rsm[5] + rsm[6] + rsm[7];
        psout[((size_t)bz * nslots + slot) * 2 + 0] = S;
        psout[((size_t)bz * nslots + slot) * 2 + 1] = SS;
    }
}

// conv1 (y<2) + conv2 (y==2)
__global__ __launch_bounds__(256) void conv_all(
        const float* __restrict__ x,
        const unsigned short* __restrict__ w1rT, const unsigned short* __restrict__ w2rT,
        const float* __restrict__ cb1, const float* __restrict__ cb2,
        unsigned short* __restrict__ c1t, unsigned short* __restrict__ c2t,
        float* __restrict__ ps1, float* __restrict__ ps2) {
    __shared__ alignas(16) char smem[49152];
    const int y = blockIdx.y, xb = blockIdx.x, bz = blockIdx.z;
    if (y < 2) {
        conv_body(smem, x, 512, w1rT, cb1, c1t, (long)Cn * T1n, T1n, 512,
                  ps1, y * 2 + xb, 4, y * 64, xb * 128, bz);
    } else {
        conv_body(smem, x, 1024, w2rT, cb2, c2t, (long)Cn * T2n, T2n, 1024,
                  ps2, xb, 2, 0, xb * 128, bz);
    }
}

// ---------------- merged layernorm apply (both scales), bf16 slab input ----------------
__global__ __launch_bounds__(256) void ln_apply_both(
        const unsigned short* __restrict__ c1t, const unsigned short* __restrict__ c2t,
        const float* __restrict__ gt1, const float* __restrict__ bt1,
        const float* __restrict__ gt2, const float* __restrict__ bt2,
        const float* __restrict__ ps1, const float* __restrict__ ps2,
        unsigned short* __restrict__ catb) {
    const int b = blockIdx.y, bx = blockIdx.x;
    const unsigned short* p;
    const float *g, *be;
    unsigned short* q;
    int LG, n, base;
    float S = 0.f, SS = 0.f;
    if (bx < 16) {
        n = Cn * T1n; LG = 7;
        p = c1t + (size_t)b * n; g = gt1; be = bt1;
        q = catb + (size_t)b * (TTn * Cn) + Tn;
#pragma unroll
        for (int s_ = 0; s_ < 4; ++s_) { S += ps1[b * 8 + s_ * 2]; SS += ps1[b * 8 + s_ * 2 + 1]; }
        base = bx * 2048;
    } else {
        n = Cn * T2n; LG = 6;
        p = c2t + (size_t)b * n; g = gt2; be = bt2;
        q = catb + (size_t)b * (TTn * Cn) + Tn + T1n;
#pragma unroll
        for (int s_ = 0; s_ < 2; ++s_) { S += ps2[b * 4 + s_ * 2]; SS += ps2[b * 4 + s_ * 2 + 1]; }
        base = (bx - 16) * 2048;
    }
    float mu = S / n;
    float rs = rsqrtf(SS / n - mu * mu + EPSf);

    int i = base + threadIdx.x * 8;
    int c = i >> LG, t = i & ((1 << LG) - 1);
    short8 vv = *(const short8*)(p + i);
    float4 g0 = *(const float4*)(g + i);
    float4 g1 = *(const float4*)(g + i + 4);
    float4 b0 = *(const float4*)(be + i);
    float4 b1 = *(const float4*)(be + i + 4);
    float4 o0, o1;
    o0.x = fmaf((b2f((unsigned short)vv[0]) - mu) * rs, g0.x, b0.x);
    o0.y = fmaf((b2f((unsigned short)vv[1]) - mu) * rs, g0.y, b0.y);
    o0.z = fmaf((b2f((unsigned short)vv[2]) - mu) * rs, g0.z, b0.z);
    o0.w = fmaf((b2f((unsigned short)vv[3]) - mu) * rs, g0.w, b0.w);
    o1.x = fmaf((b2f((unsigned short)vv[4]) - mu) * rs, g1.x, b1.x);
    o1.y = fmaf((b2f((unsigned short)vv[5]) - mu) * rs, g1.y, b1.y);
    o1.z = fmaf((b2f((unsigned short)vv[6]) - mu) * rs, g1.z, b1.z);
    o1.w = fmaf((b2f((unsigned short)vv[7]) - mu) * rs, g1.w, b1.w);
    *(short8*)(q + (size_t)c * TTn + t) = cvt8(o0, o1);
}

// ---------------- TriU GEMM, flat-N, dbuf, 1 barrier/k-tile, XCD-local B-panel chains ----------------
template<int EPI>
__global__ __launch_bounds__(256)
void triu_db(const unsigned short* __restrict__ Asrc,
             const unsigned short* __restrict__ Bsrc,
             const float* __restrict__ bias,
             void* __restrict__ Cv) {
    const int tid = threadIdx.x;
    const int lane = tid & 63;
    const int wid = tid >> 6;
    const int wr = wid >> 1, wc = wid & 1;

    const int bid = blockIdx.x;
    const int xcd = bid & 7, seq = bid >> 3;
    const int m0 = (seq % 7) * 64;
    const long n0 = (long)(xcd * 32 + seq / 7) * 128;   // flat (b,c) row index

    __shared__ unsigned short As[2][64 * 64];   // 16 KB
    __shared__ unsigned short Bs[2][128 * 64];  // 32 KB

    const int ar = tid >> 2, akq = tid & 3;
    const int bn_ = tid >> 1, bkh = (tid & 1) * 32;

    const unsigned short* Ap = Asrc + (size_t)(m0 + ar) * TTn + akq * 16;
    const unsigned short* Bp = Bsrc + (size_t)(n0 + bn_) * TTn + bkh;

    const int awb = ar * 128 + akq * 32;
    const int aswz = (ar & 7) << 4;
    const int bwb = bn_ * 128 + bkh * 2;
    const int bswz = (bn_ & 7) << 4;

    short8 ra0, ra1, rb[4];
    auto loadAB = [&](int k0) {
        ra0 = *(const short8*)(Ap + k0);
        ra1 = *(const short8*)(Ap + k0 + 8);
#pragma unroll
        for (int j = 0; j < 4; ++j) rb[j] = *(const short8*)(Bp + k0 + j * 8);
    };
    auto stage = [&](int buf) {
        char* AsB = (char*)As[buf];
        char* BsB = (char*)Bs[buf];
        *(short8*)(AsB + ((awb) ^ aswz)) = ra0;
        *(short8*)(AsB + ((awb + 16) ^ aswz)) = ra1;
#pragma unroll
        for (int j = 0; j < 4; ++j)
            *(short8*)(BsB + ((bwb + j * 16) ^ bswz)) = rb[j];
    };

    const int fl = lane & 15;
    const int fkb = (lane >> 4) * 16;
    const int amb = (wr * 32 + fl) * 128;
    const int bnb = (wc * 64 + fl) * 128;
    const int fswz = (fl & 7) << 4;

    f32x4 acc[2][4];
#pragma unroll
    for (int i = 0; i < 2; ++i)
#pragma unroll
        for (int j = 0; j < 4; ++j) acc[i][j] = (f32x4){0.f, 0.f, 0.f, 0.f};

    const int nkt = (m0 >> 6) + 1;   // triangular skip

    loadAB(0);
    stage(0);
    __syncthreads();
    for (int kt = 0; kt < nkt; ++kt) {
        const int cur = kt & 1;
        if (kt + 1 < nkt) loadAB((kt + 1) * 64);   // globals in flight during MFMA
        char* AsB = (char*)As[cur];
        char* BsB = (char*)Bs[cur];
#pragma unroll
        for (int ks = 0; ks < 2; ++ks) {
            const int kb = ks * 64 + fkb;
            short8 af0 = *(const short8*)(AsB + ((amb + kb) ^ fswz));
            short8 af1 = *(const short8*)(AsB + ((amb + 2048 + kb) ^ fswz));
            short8 bf0 = *(const short8*)(BsB + ((bnb + kb) ^ fswz));
            short8 bf1 = *(const short8*)(BsB + ((bnb + 2048 + kb) ^ fswz));
            short8 bf2 = *(const short8*)(BsB + ((bnb + 4096 + kb) ^ fswz));
            short8 bf3 = *(const short8*)(BsB + ((bnb + 6144 + kb) ^ fswz));
            acc[0][0] = __builtin_amdgcn_mfma_f32_16x16x32_bf16(af0, bf0, acc[0][0], 0, 0, 0);
            acc[0][1] = __builtin_amdgcn_mfma_f32_16x16x32_bf16(af0, bf1, acc[0][1], 0, 0, 0);
            acc[0][2] = __builtin_amdgcn_mfma_f32_16x16x32_bf16(af0, bf2, acc[0][2], 0, 0, 0);
            acc[0][3] = __builtin_amdgcn_mfma_f32_16x16x32_bf16(af0, bf3, acc[0][3], 0, 0, 0);
            acc[1][0] = __builtin_amdgcn_mfma_f32_16x16x32_bf16(af1, bf0, acc[1][0], 0, 0, 0);
            acc[1][1] = __builtin_amdgcn_mfma_f32_16x16x32_bf16(af1, bf1, acc[1][1], 0, 0, 0);
            acc[1][2] = __builtin_amdgcn_mfma_f32_16x16x32_bf16(af1, bf2, acc[1][2], 0, 0, 0);
            acc[1][3] = __builtin_amdgcn_mfma_f32_16x16x32_bf16(af1, bf3, acc[1][3], 0, 0, 0);
        }
        if (kt + 1 < nkt) stage(cur ^ 1);
        __syncthreads();
    }

    const int lrow = (lane >> 4) * 4;
#pragma unroll
    for (int mf = 0; mf < 2; ++mf) {
        const int trow = m0 + wr * 32 + mf * 16 + lrow;
        f32x4 bv = *(const f32x4*)(bias + trow);
#pragma unroll
        for (int nf = 0; nf < 4; ++nf) {
            const long coln = n0 + wc * 64 + nf * 16 + fl;
            f32x4 v = acc[mf][nf] + bv;
            if (EPI == 1) {
                unsigned short* Cb = (unsigned short*)Cv + (size_t)coln * TTn + trow;
                short4v pk;
#pragma unroll
                for (int r = 0; r < 4; ++r) {
                    float t = v[r];
                    float u = fminf(fmaxf(t + 3.f, 0.f), 6.f);
                    t = t * u * (1.f / 6.f);
                    pk[r] = (short)f2b(t);
                }
                *(short4v*)Cb = pk;
            } else {
                const int b = (int)(coln >> 8), c = (int)(coln & 255);
                float* Cb = (float*)Cv + ((size_t)b * TTn + trow) * Cn + c;
#pragma unroll
                for (int r = 0; r < 4; ++r) Cb[(size_t)r * Cn] = v[r];
            }
        }
    }
}

// ---------------- launch ----------------
extern "C" void kernel_launch(void* const* d_in, const int* in_sizes, int n_in,
                              void* d_out, int out_size, void* d_ws, size_t ws_size,
                              hipStream_t stream) {
    const float* x    = (const float*)d_in[0];
    const float* cw1  = (const float*)d_in[1];
    const float* cb1  = (const float*)d_in[2];
    const float* cw2  = (const float*)d_in[3];
    const float* cb2  = (const float*)d_in[4];
    const float* ln1g = (const float*)d_in[5];
    const float* ln1b = (const float*)d_in[6];
    const float* ln2g = (const float*)d_in[7];
    const float* ln2b = (const float*)d_in[8];
    const float* tw1  = (const float*)d_in[9];
    const float* tb1  = (const float*)d_in[10];
    const float* tw2  = (const float*)d_in[11];
    const float* tb2  = (const float*)d_in[12];
    float* out = (float*)d_out;

    char* w = (char*)d_ws;
    unsigned short* catb = (unsigned short*)w;                  // bf16 [B][C][448]  29,360,128 B
    unsigned short* z1b  = (unsigned short*)(w + 29360128);     // bf16 [B][C][448]  29,360,128 B
    unsigned short* c1t  = (unsigned short*)(w + 58720256);     // bf16 [B][C][128]   8,388,608 B
    unsigned short* c2t  = (unsigned short*)(w + 67108864);     // bf16 [B][C][64]    4,194,304 B
    unsigned short* w1rT = (unsigned short*)(w + 71303168);     // 262,144 B
    unsigned short* w2rT = (unsigned short*)(w + 71565312);     // 524,288 B
    unsigned short* wm1b = (unsigned short*)(w + 72089600);     // 401,408 B
    unsigned short* wm2b = (unsigned short*)(w + 72491008);     // 401,408 B
    float*          gt1  = (float*)(w + 72892416);              // 131,072 B
    float*          bt1  = (float*)(w + 73023488);              // 131,072 B
    float*          gt2  = (float*)(w + 73154560);              // 65,536 B
    float*          bt2  = (float*)(w + 73220096);              // 65,536 B
    float*          ps1  = (float*)(w + 73285632);              // [B][4][2] = 4096 B
    float*          ps2  = (float*)(w + 73289728);              // [B][2][2] = 2048 B

    // 1) prep + x-transpose in one launch (2048 xpose tiles + 3488 prep chunks)
    prep_xpose<<<5536, 256, 0, stream>>>(x, cw1, cw2, tw1, tw2, ln1g, ln1b, ln2g, ln2b,
                                         catb, w1rT, w2rT, wm1b, wm2b, gt1, bt1, gt2, bt2);

    // 2) conv1 + conv2 (+ LN partial sums), bf16 slabs
    conv_all<<<dim3(2, 3, Bn), 256, 0, stream>>>(x, w1rT, w2rT, cb1, cb2, c1t, c2t, ps1, ps2);

    // 3) both layernorm applies -> catb rows [256,448)
    ln_apply_both<<<dim3(24, Bn), 256, 0, stream>>>(c1t, c2t, gt1, bt1, gt2, bt2, ps1, ps2, catb);

    // 4) TriU layer 1 -> z1b (bf16, hardswish); flat-N dbuf GEMM, XCD-swizzled
    triu_db<1><<<1792, 256, 0, stream>>>(wm1b, catb, tb1, z1b);

    // 5) TriU layer 2 -> out (f32 [b][t][c])
    triu_db<2><<<1792, 256, 0, stream>>>(wm2b, z1b, tb2, out);
}

// Round 16
// 91.599 us; speedup vs baseline: 2.9105x; 1.0186x over previous
//
#include <hip/hip_runtime.h>
#include <hip/hip_bf16.h>

#define Bn   128
#define Tn   256
#define Cn   256
#define T1n  128
#define T2n  64
#define TTn  448
#define EPSf 1e-5f

typedef __attribute__((ext_vector_type(8))) short short8;
typedef __attribute__((ext_vector_type(4))) short short4v;
typedef __attribute__((ext_vector_type(4))) float f32x4;

__device__ __forceinline__ unsigned short f2b(float f) {
    union { __hip_bfloat16 h; unsigned short u; } cv;
    cv.h = __float2bfloat16(f);   // RNE
    return cv.u;
}

__device__ __forceinline__ float b2f(unsigned short u) {
    union { float f; unsigned v; } c;
    c.v = (unsigned)u << 16;
    return c.f;
}

__device__ __forceinline__ short8 cvt8(float4 a, float4 b) {
    short8 r;
    r[0] = (short)f2b(a.x); r[1] = (short)f2b(a.y); r[2] = (short)f2b(a.z); r[3] = (short)f2b(a.w);
    r[4] = (short)f2b(b.x); r[5] = (short)f2b(b.y); r[6] = (short)f2b(b.z); r[7] = (short)f2b(b.w);
    return r;
}

// direct global->LDS DMA, 16B per lane (wave-uniform LDS base + lane*16)
__device__ __forceinline__ void gload_lds16(const void* g, void* l) {
    __builtin_amdgcn_global_load_lds(
        (const __attribute__((address_space(1))) unsigned int*)g,
        (__attribute__((address_space(3))) unsigned int*)l, 16, 0, 0);
}

// ---------------- merged prep + x-transpose ----------------
__global__ __launch_bounds__(256) void prep_xpose(
        const float* __restrict__ x,
        const float* __restrict__ cw1, const float* __restrict__ cw2,
        const float* __restrict__ tw1, const float* __restrict__ tw2,
        const float* __restrict__ ln1g, const float* __restrict__ ln1b,
        const float* __restrict__ ln2g, const float* __restrict__ ln2b,
        unsigned short* __restrict__ catb,
        unsigned short* __restrict__ w1rT, unsigned short* __restrict__ w2rT,
        unsigned short* __restrict__ wm1b, unsigned short* __restrict__ wm2b,
        float* __restrict__ gt1, float* __restrict__ bt1,
        float* __restrict__ gt2, float* __restrict__ bt2) {
    __shared__ float tl[64][65];
    const int vb = blockIdx.x;
    if (vb < 2048) {
        int b = vb >> 4, r = vb & 15;
        int t0 = ((r >> 2) & 3) * 64, c0 = (r & 3) * 64;
        const float* xp = x + (size_t)b * Tn * Cn;
        int lr = threadIdx.x >> 4;
        int lc = (threadIdx.x & 15) * 4;
#pragma unroll
        for (int rr = 0; rr < 4; ++rr) {
            int row = lr + rr * 16;
            float4 v = *(const float4*)(xp + (size_t)(t0 + row) * Cn + c0 + lc);
            tl[lc + 0][row] = v.x; tl[lc + 1][row] = v.y;
            tl[lc + 2][row] = v.z; tl[lc + 3][row] = v.w;
        }
        __syncthreads();
        int cr = threadIdx.x >> 2, tq = (threadIdx.x & 3) * 16;
        unsigned short* qp = catb + (size_t)b * (TTn * Cn) + (size_t)(c0 + cr) * TTn + t0 + tq;
        short8 o0, o1;
#pragma unroll
        for (int j = 0; j < 8; ++j) {
            o0[j] = (short)f2b(tl[cr][tq + j]);
            o1[j] = (short)f2b(tl[cr][tq + 8 + j]);
        }
        *(short8*)(qp) = o0;
        *(short8*)(qp + 8) = o1;
        return;
    }
    int idx = (vb - 2048) * 256 + threadIdx.x;
    if (idx < 131072) {
        int co = idx >> 9, r = idx & 511, k = r >> 8, ci = r & 255;
        w1rT[idx] = f2b(cw1[(size_t)co * 512 + ci * 2 + k]);
    } else if ((idx -= 131072) < 262144) {
        int co = idx >> 10, r = idx & 1023, k = r >> 8, ci = r & 255;
        w2rT[idx] = f2b(cw2[(size_t)co * 1024 + ci * 4 + k]);
    } else if ((idx -= 262144) < 200704) {
        int i = idx / TTn, j = idx % TTn;
        wm1b[idx] = (j <= i) ? f2b(tw1[(size_t)j * TTn + i]) : (unsigned short)0;
    } else if ((idx -= 200704) < 200704) {
        int i = idx / TTn, j = idx % TTn;
        wm2b[idx] = (j <= i) ? f2b(tw2[(size_t)j * TTn + i]) : (unsigned short)0;
    } else if ((idx -= 200704) < 32768) {
        int c = idx >> 7, r = idx & 127;
        gt1[idx] = ln1g[(size_t)r * Cn + c];
    } else if ((idx -= 32768) < 32768) {
        int c = idx >> 7, r = idx & 127;
        bt1[idx] = ln1b[(size_t)r * Cn + c];
    } else if ((idx -= 32768) < 16384) {
        int c = idx >> 6, r = idx & 63;
        gt2[idx] = ln2g[(size_t)r * Cn + c];
    } else if ((idx -= 16384) < 16384) {
        int c = idx >> 6, r = idx & 63;
        bt2[idx] = ln2b[(size_t)r * Cn + c];
    }
}

// ---------------- conv GEMM body (BM=64 BN=128 BK=64), dbuf, bf16 slab output ----------------
__device__ __forceinline__ void conv_body(char* smem,
        const float* __restrict__ x, int lda,
        const unsigned short* __restrict__ Bw,
        const float* __restrict__ bias,
        unsigned short* __restrict__ Cout, long cstride, int ldc, int K,
        float* __restrict__ psout, int slot, int nslots,
        int m0, int n0, int bz) {
    const int tid = threadIdx.x;
    const int lane = tid & 63;
    const int wid = tid >> 6;
    const int wr = wid >> 1, wc = wid & 1;

    const int ar = tid >> 2, akq = tid & 3;
    const int bn_ = tid >> 1, bkh = (tid & 1) * 32;

    const float* Afp = x + (size_t)bz * (Tn * Cn) + (size_t)(m0 + ar) * lda + akq * 16;
    const unsigned short* Bp = Bw + (size_t)(n0 + bn_) * K + bkh;

    const int awb = ar * 128 + akq * 32;
    const int aswz = (ar & 7) << 4;
    const int bwb = bn_ * 128 + bkh * 2;
    const int bswz = (bn_ & 7) << 4;

    short8 ra0, ra1, rb0, rb1, rb2, rb3;
    auto loadA = [&](int k0) {
        const float* p = Afp + k0;
        float4 v0 = *(const float4*)(p);
        float4 v1 = *(const float4*)(p + 4);
        float4 v2 = *(const float4*)(p + 8);
        float4 v3 = *(const float4*)(p + 12);
        ra0 = cvt8(v0, v1);
        ra1 = cvt8(v2, v3);
    };
    auto loadB = [&](int k0) {
        rb0 = *(const short8*)(Bp + k0);
        rb1 = *(const short8*)(Bp + k0 + 8);
        rb2 = *(const short8*)(Bp + k0 + 16);
        rb3 = *(const short8*)(Bp + k0 + 24);
    };
    auto stage = [&](int buf) {
        char* AsB = smem + buf * 8192;
        char* BsB = smem + 16384 + buf * 16384;
        *(short8*)(AsB + ((awb) ^ aswz)) = ra0;
        *(short8*)(AsB + ((awb + 16) ^ aswz)) = ra1;
        *(short8*)(BsB + ((bwb) ^ bswz)) = rb0;
        *(short8*)(BsB + ((bwb + 16) ^ bswz)) = rb1;
        *(short8*)(BsB + ((bwb + 32) ^ bswz)) = rb2;
        *(short8*)(BsB + ((bwb + 48) ^ bswz)) = rb3;
    };

    const int fl = lane & 15;
    const int fkb = (lane >> 4) * 16;
    const int amb = (wr * 32 + fl) * 128;
    const int bnb = (wc * 64 + fl) * 128;
    const int fswz = (fl & 7) << 4;

    f32x4 acc[2][4];
#pragma unroll
    for (int i = 0; i < 2; ++i)
#pragma unroll
        for (int j = 0; j < 4; ++j) acc[i][j] = (f32x4){0.f, 0.f, 0.f, 0.f};

    const int nkt = K >> 6;
    loadA(0); loadB(0);
    stage(0);
    __syncthreads();
    for (int kt = 0; kt < nkt; ++kt) {
        const int cur = kt & 1;
        if (kt + 1 < nkt) { loadA((kt + 1) * 64); loadB((kt + 1) * 64); }
        char* AsB = smem + cur * 8192;
        char* BsB = smem + 16384 + cur * 16384;
#pragma unroll
        for (int ks = 0; ks < 2; ++ks) {
            const int kb = ks * 64 + fkb;
            short8 af0 = *(const short8*)(AsB + ((amb + kb) ^ fswz));
            short8 af1 = *(const short8*)(AsB + ((amb + 2048 + kb) ^ fswz));
            short8 bf0 = *(const short8*)(BsB + ((bnb + kb) ^ fswz));
            short8 bf1 = *(const short8*)(BsB + ((bnb + 2048 + kb) ^ fswz));
            short8 bf2 = *(const short8*)(BsB + ((bnb + 4096 + kb) ^ fswz));
            short8 bf3 = *(const short8*)(BsB + ((bnb + 6144 + kb) ^ fswz));
            acc[0][0] = __builtin_amdgcn_mfma_f32_16x16x32_bf16(af0, bf0, acc[0][0], 0, 0, 0);
            acc[0][1] = __builtin_amdgcn_mfma_f32_16x16x32_bf16(af0, bf1, acc[0][1], 0, 0, 0);
            acc[0][2] = __builtin_amdgcn_mfma_f32_16x16x32_bf16(af0, bf2, acc[0][2], 0, 0, 0);
            acc[0][3] = __builtin_amdgcn_mfma_f32_16x16x32_bf16(af0, bf3, acc[0][3], 0, 0, 0);
            acc[1][0] = __builtin_amdgcn_mfma_f32_16x16x32_bf16(af1, bf0, acc[1][0], 0, 0, 0);
            acc[1][1] = __builtin_amdgcn_mfma_f32_16x16x32_bf16(af1, bf1, acc[1][1], 0, 0, 0);
            acc[1][2] = __builtin_amdgcn_mfma_f32_16x16x32_bf16(af1, bf2, acc[1][2], 0, 0, 0);
            acc[1][3] = __builtin_amdgcn_mfma_f32_16x16x32_bf16(af1, bf3, acc[1][3], 0, 0, 0);
        }
        if (kt + 1 < nkt) stage(cur ^ 1);
        __syncthreads();
    }

    const int lrow = (lane >> 4) * 4;
    float s_ = 0.f, ss_ = 0.f;
#pragma unroll
    for (int mf = 0; mf < 2; ++mf) {
        const int trow = m0 + wr * 32 + mf * 16 + lrow;
#pragma unroll
        for (int nf = 0; nf < 4; ++nf) {
            const int col = n0 + wc * 64 + nf * 16 + fl;
            f32x4 v = acc[mf][nf];
            v += bias[col];
            short4v pk;
#pragma unroll
            for (int r = 0; r < 4; ++r) {
                s_ += v[r]; ss_ = fmaf(v[r], v[r], ss_);
                pk[r] = (short)f2b(v[r]);
            }
            unsigned short* Cb = Cout + (size_t)bz * cstride + (size_t)col * ldc + trow;
            *(short4v*)Cb = pk;
        }
    }

#pragma unroll
    for (int o = 32; o > 0; o >>= 1) { s_ += __shfl_down(s_, o); ss_ += __shfl_down(ss_, o); }
    float* rsm = (float*)smem;
    if (lane == 0) { rsm[wid] = s_; rsm[wid + 4] = ss_; }
    __syncthreads();
    if (tid == 0) {
        float S = rsm[0] + rsm[1] + rsm[2] + rsm[3];
        float SS = rsm[4] + rsm[5] + rsm[6] + rsm[7];
        psout[((size_t)bz * nslots + slot) * 2 + 0] = S;
        psout[((size_t)bz * nslots + slot) * 2 + 1] = SS;
    }
}

// conv1 (y<2) + conv2 (y==2)
__global__ __launch_bounds__(256) void conv_all(
        const float* __restrict__ x,
        const unsigned short* __restrict__ w1rT, const unsigned short* __restrict__ w2rT,
        const float* __restrict__ cb1, const float* __restrict__ cb2,
        unsigned short* __restrict__ c1t, unsigned short* __restrict__ c2t,
        float* __restrict__ ps1, float* __restrict__ ps2) {
    __shared__ alignas(16) char smem[49152];
    const int y = blockIdx.y, xb = blockIdx.x, bz = blockIdx.z;
    if (y < 2) {
        conv_body(smem, x, 512, w1rT, cb1, c1t, (long)Cn * T1n, T1n, 512,
                  ps1, y * 2 + xb, 4, y * 64, xb * 128, bz);
    } else {
        conv_body(smem, x, 1024, w2rT, cb2, c2t, (long)Cn * T2n, T2n, 1024,
                  ps2, xb, 2, 0, xb * 128, bz);
    }
}

// ---------------- merged layernorm apply (both scales), bf16 slab input ----------------
__global__ __launch_bounds__(256) void ln_apply_both(
        const unsigned short* __restrict__ c1t, const unsigned short* __restrict__ c2t,
        const float* __restrict__ gt1, const float* __restrict__ bt1,
        const float* __restrict__ gt2, const float* __restrict__ bt2,
        const float* __restrict__ ps1, const float* __restrict__ ps2,
        unsigned short* __restrict__ catb) {
    const int b = blockIdx.y, bx = blockIdx.x;
    const unsigned short* p;
    const float *g, *be;
    unsigned short* q;
    int LG, n, base;
    float S = 0.f, SS = 0.f;
    if (bx < 16) {
        n = Cn * T1n; LG = 7;
        p = c1t + (size_t)b * n; g = gt1; be = bt1;
        q = catb + (size_t)b * (TTn * Cn) + Tn;
#pragma unroll
        for (int s_ = 0; s_ < 4; ++s_) { S += ps1[b * 8 + s_ * 2]; SS += ps1[b * 8 + s_ * 2 + 1]; }
        base = bx * 2048;
    } else {
        n = Cn * T2n; LG = 6;
        p = c2t + (size_t)b * n; g = gt2; be = bt2;
        q = catb + (size_t)b * (TTn * Cn) + Tn + T1n;
#pragma unroll
        for (int s_ = 0; s_ < 2; ++s_) { S += ps2[b * 4 + s_ * 2]; SS += ps2[b * 4 + s_ * 2 + 1]; }
        base = (bx - 16) * 2048;
    }
    float mu = S / n;
    float rs = rsqrtf(SS / n - mu * mu + EPSf);

    int i = base + threadIdx.x * 8;
    int c = i >> LG, t = i & ((1 << LG) - 1);
    short8 vv = *(const short8*)(p + i);
    float4 g0 = *(const float4*)(g + i);
    float4 g1 = *(const float4*)(g + i + 4);
    float4 b0 = *(const float4*)(be + i);
    float4 b1 = *(const float4*)(be + i + 4);
    float4 o0, o1;
    o0.x = fmaf((b2f((unsigned short)vv[0]) - mu) * rs, g0.x, b0.x);
    o0.y = fmaf((b2f((unsigned short)vv[1]) - mu) * rs, g0.y, b0.y);
    o0.z = fmaf((b2f((unsigned short)vv[2]) - mu) * rs, g0.z, b0.z);
    o0.w = fmaf((b2f((unsigned short)vv[3]) - mu) * rs, g0.w, b0.w);
    o1.x = fmaf((b2f((unsigned short)vv[4]) - mu) * rs, g1.x, b1.x);
    o1.y = fmaf((b2f((unsigned short)vv[5]) - mu) * rs, g1.y, b1.y);
    o1.z = fmaf((b2f((unsigned short)vv[6]) - mu) * rs, g1.z, b1.z);
    o1.w = fmaf((b2f((unsigned short)vv[7]) - mu) * rs, g1.w, b1.w);
    *(short8*)(q + (size_t)c * TTn + t) = cvt8(o0, o1);
}

// ---------------- TriU GEMM: flat-N, dbuf, XCD-local chains, global_load_lds staging ----------------
// A: bf16 [448][448] tri-masked. B: bf16 flat [32768][448]. BM=64 BN=128 BK=64.
// Staging: 24 x 1KB chunks per buffer via global_load_lds width-16 (6 per wave).
// LDS is linear-per-chunk; the XOR swizzle is applied to the per-lane GLOBAL source byte
// (pre-swizzled-source pattern), so LDS contents are bit-identical to the old stage().
// m order reversed within each panel chain (long blocks dispatch first -> better tail).
template<int EPI>
__global__ __launch_bounds__(256)
void triu_db(const unsigned short* __restrict__ Asrc,
             const unsigned short* __restrict__ Bsrc,
             const float* __restrict__ bias,
             void* __restrict__ Cv) {
    const int tid = threadIdx.x;
    const int lane = tid & 63;
    const int wid = tid >> 6;
    const int wr = wid >> 1, wc = wid & 1;

    const int bid = blockIdx.x;
    const int xcd = bid & 7, seq = bid >> 3;
    const int mi = 6 - (seq % 7);                       // long-first within chain
    const int m0 = mi * 64;
    const long n0 = (long)(xcd * 32 + seq / 7) * 128;   // flat (b,c) row index

    __shared__ unsigned short As[2][64 * 64];   // 16 KB
    __shared__ unsigned short Bs[2][128 * 64];  // 32 KB

    // --- staging setup: wave wid covers chunks [wid*6, wid*6+6) of 24 ---
    const int l8 = lane >> 3, l7 = lane & 7;
    const int boff = (l7 * 16) ^ ((l8 & 7) << 4);       // pre-swizzled byte-in-row
    const char* srcb[6];
#pragma unroll
    for (int i = 0; i < 6; ++i) {
        int c = wid * 6 + i;
        long row = (c < 8) ? (long)(m0 + c * 8 + l8) : (n0 + (long)(c - 8) * 8 + l8);
        const char* basep = (c < 8) ? (const char*)Asrc : (const char*)Bsrc;
        srcb[i] = basep + row * (TTn * 2) + boff;
    }
    char* a0 = (char*)As[0]; char* a1 = (char*)As[1];
    char* b0 = (char*)Bs[0]; char* b1 = (char*)Bs[1];
    auto issue = [&](int buf, int kbyte) {
        char* ab = buf ? a1 : a0;
        char* bb = buf ? b1 : b0;
#pragma unroll
        for (int i = 0; i < 6; ++i) {
            int c = wid * 6 + i;
            char* lp = (c < 8) ? (ab + c * 1024) : (bb + (c - 8) * 1024);
            gload_lds16(srcb[i] + kbyte, lp);
        }
    };

    // --- fragment read path (unchanged) ---
    const int fl = lane & 15;
    const int fkb = (lane >> 4) * 16;
    const int amb = (wr * 32 + fl) * 128;
    const int bnb = (wc * 64 + fl) * 128;
    const int fswz = (fl & 7) << 4;

    f32x4 acc[2][4];
#pragma unroll
    for (int i = 0; i < 2; ++i)
#pragma unroll
        for (int j = 0; j < 4; ++j) acc[i][j] = (f32x4){0.f, 0.f, 0.f, 0.f};

    const int nkt = mi + 1;   // triangular skip

    issue(0, 0);
    __syncthreads();          // drains the DMA (vmcnt) + barrier
    for (int kt = 0; kt < nkt; ++kt) {
        const int cur = kt & 1;
        if (kt + 1 < nkt) issue(cur ^ 1, (kt + 1) * 128);   // async DMA into alternate buffer
        char* AsB = cur ? a1 : a0;
        char* BsB = cur ? b1 : b0;
#pragma unroll
        for (int ks = 0; ks < 2; ++ks) {
            const int kb = ks * 64 + fkb;
            short8 af0 = *(const short8*)(AsB + ((amb + kb) ^ fswz));
            short8 af1 = *(const short8*)(AsB + ((amb + 2048 + kb) ^ fswz));
            short8 bf0 = *(const short8*)(BsB + ((bnb + kb) ^ fswz));
            short8 bf1 = *(const short8*)(BsB + ((bnb + 2048 + kb) ^ fswz));
            short8 bf2 = *(const short8*)(BsB + ((bnb + 4096 + kb) ^ fswz));
            short8 bf3 = *(const short8*)(BsB + ((bnb + 6144 + kb) ^ fswz));
            acc[0][0] = __builtin_amdgcn_mfma_f32_16x16x32_bf16(af0, bf0, acc[0][0], 0, 0, 0);
            acc[0][1] = __builtin_amdgcn_mfma_f32_16x16x32_bf16(af0, bf1, acc[0][1], 0, 0, 0);
            acc[0][2] = __builtin_amdgcn_mfma_f32_16x16x32_bf16(af0, bf2, acc[0][2], 0, 0, 0);
            acc[0][3] = __builtin_amdgcn_mfma_f32_16x16x32_bf16(af0, bf3, acc[0][3], 0, 0, 0);
            acc[1][0] = __builtin_amdgcn_mfma_f32_16x16x32_bf16(af1, bf0, acc[1][0], 0, 0, 0);
            acc[1][1] = __builtin_amdgcn_mfma_f32_16x16x32_bf16(af1, bf1, acc[1][1], 0, 0, 0);
            acc[1][2] = __builtin_amdgcn_mfma_f32_16x16x32_bf16(af1, bf2, acc[1][2], 0, 0, 0);
            acc[1][3] = __builtin_amdgcn_mfma_f32_16x16x32_bf16(af1, bf3, acc[1][3], 0, 0, 0);
        }
        __syncthreads();   // drains DMA for cur^1 + fences reads of cur before overwrite
    }

    const int lrow = (lane >> 4) * 4;
#pragma unroll
    for (int mf = 0; mf < 2; ++mf) {
        const int trow = m0 + wr * 32 + mf * 16 + lrow;
        f32x4 bv = *(const f32x4*)(bias + trow);
#pragma unroll
        for (int nf = 0; nf < 4; ++nf) {
            const long coln = n0 + wc * 64 + nf * 16 + fl;
            f32x4 v = acc[mf][nf] + bv;
            if (EPI == 1) {
                unsigned short* Cb = (unsigned short*)Cv + (size_t)coln * TTn + trow;
                short4v pk;
#pragma unroll
                for (int r = 0; r < 4; ++r) {
                    float t = v[r];
                    float u = fminf(fmaxf(t + 3.f, 0.f), 6.f);
                    t = t * u * (1.f / 6.f);
                    pk[r] = (short)f2b(t);
                }
                *(short4v*)Cb = pk;
            } else {
                const int b = (int)(coln >> 8), c = (int)(coln & 255);
                float* Cb = (float*)Cv + ((size_t)b * TTn + trow) * Cn + c;
#pragma unroll
                for (int r = 0; r < 4; ++r) Cb[(size_t)r * Cn] = v[r];
            }
        }
    }
}

// ---------------- launch ----------------
extern "C" void kernel_launch(void* const* d_in, const int* in_sizes, int n_in,
                              void* d_out, int out_size, void* d_ws, size_t ws_size,
                              hipStream_t stream) {
    const float* x    = (const float*)d_in[0];
    const float* cw1  = (const float*)d_in[1];
    const float* cb1  = (const float*)d_in[2];
    const float* cw2  = (const float*)d_in[3];
    const float* cb2  = (const float*)d_in[4];
    const float* ln1g = (const float*)d_in[5];
    const float* ln1b = (const float*)d_in[6];
    const float* ln2g = (const float*)d_in[7];
    const float* ln2b = (const float*)d_in[8];
    const float* tw1  = (const float*)d_in[9];
    const float* tb1  = (const float*)d_in[10];
    const float* tw2  = (const float*)d_in[11];
    const float* tb2  = (const float*)d_in[12];
    float* out = (float*)d_out;

    char* w = (char*)d_ws;
    unsigned short* catb = (unsigned short*)w;                  // bf16 [B][C][448]  29,360,128 B
    unsigned short* z1b  = (unsigned short*)(w + 29360128);     // bf16 [B][C][448]  29,360,128 B
    unsigned short* c1t  = (unsigned short*)(w + 58720256);     // bf16 [B][C][128]   8,388,608 B
    unsigned short* c2t  = (unsigned short*)(w + 67108864);     // bf16 [B][C][64]    4,194,304 B
    unsigned short* w1rT = (unsigned short*)(w + 71303168);     // 262,144 B
    unsigned short* w2rT = (unsigned short*)(w + 71565312);     // 524,288 B
    unsigned short* wm1b = (unsigned short*)(w + 72089600);     // 401,408 B
    unsigned short* wm2b = (unsigned short*)(w + 72491008);     // 401,408 B
    float*          gt1  = (float*)(w + 72892416);              // 131,072 B
    float*          bt1  = (float*)(w + 73023488);              // 131,072 B
    float*          gt2  = (float*)(w + 73154560);              // 65,536 B
    float*          bt2  = (float*)(w + 73220096);              // 65,536 B
    float*          ps1  = (float*)(w + 73285632);              // [B][4][2] = 4096 B
    float*          ps2  = (float*)(w + 73289728);              // [B][2][2] = 2048 B

    // 1) prep + x-transpose
    prep_xpose<<<5536, 256, 0, stream>>>(x, cw1, cw2, tw1, tw2, ln1g, ln1b, ln2g, ln2b,
                                         catb, w1rT, w2rT, wm1b, wm2b, gt1, bt1, gt2, bt2);

    // 2) conv1 + conv2 (+ LN partial sums), bf16 slabs
    conv_all<<<dim3(2, 3, Bn), 256, 0, stream>>>(x, w1rT, w2rT, cb1, cb2, c1t, c2t, ps1, ps2);

    // 3) both layernorm applies -> catb rows [256,448)
    ln_apply_both<<<dim3(24, Bn), 256, 0, stream>>>(c1t, c2t, gt1, bt1, gt2, bt2, ps1, ps2, catb);

    // 4) TriU layer 1 -> z1b (bf16, hardswish)
    triu_db<1><<<1792, 256, 0, stream>>>(wm1b, catb, tb1, z1b);

    // 5) TriU layer 2 -> out (f32 [b][t][c])
    triu_db<2><<<1792, 256, 0, stream>>>(wm2b, z1b, tb2, out);
}